// Round 4
// baseline (232.787 us; speedup 1.0000x reference)
//
#include <hip/hip_runtime.h>
#include <math.h>

#define Bn 4
#define Cn 256
#define Hn 64
#define Wn 64
#define On 256
#define HWn 4096
#define Pn 16384   // B*H*W
#define Kc 2304    // 9*256

// s_waitcnt imm: vmcnt=63 (no wait), expcnt=7 (no wait), lgkmcnt=0 (drain LDS)
#define LGKM0 0xc07f

typedef _Float16 half8 __attribute__((ext_vector_type(8)));
typedef float floatx4 __attribute__((ext_vector_type(4)));

// ---------------------------------------------------------------------------
// ONE init kernel: blocks 0..4095 = fp32 NCHW -> f16 NHWC transpose;
// 4096..4863 = main-weight pack (layer l = (bx-4096)>>8, n = &255);
// 4864..4959 = offset-weight pack (layer l = (bx-4864)>>5, oc = &31).
__global__ void k_init(const float* __restrict__ x, _Float16* __restrict__ act0,
                       const float* __restrict__ w0, const float* __restrict__ w1,
                       const float* __restrict__ w2, const float* __restrict__ wo0,
                       const float* __restrict__ wo1, const float* __restrict__ wo2,
                       _Float16* __restrict__ wtp, _Float16* __restrict__ wbop) {
  int bx = blockIdx.x;
  int tid = threadIdx.x;
  if (bx < 4096) {
    // transpose tile: R=Cn rows, Cc=HWn cols; out[b][hw][ch] = in[b][ch][hw]
    __shared__ float tile[32][33];
    int cx = bx & 127, cy = (bx >> 7) & 7, b = bx >> 10;
    int c0 = cx * 32, r0 = cy * 32;
    int tx = tid & 31, ty = tid >> 5;
    const float* ib = x + (size_t)b * Cn * HWn;
    _Float16* ob = act0 + (size_t)b * Cn * HWn;
#pragma unroll
    for (int i = 0; i < 32; i += 8)
      tile[ty + i][tx] = ib[(size_t)(r0 + ty + i) * HWn + (c0 + tx)];
    __syncthreads();
#pragma unroll
    for (int i = 0; i < 32; i += 8)
      ob[(size_t)(c0 + ty + i) * Cn + (r0 + tx)] = (_Float16)tile[tx][ty + i];
  } else if (bx < 4864) {
    int b2 = bx - 4096;
    int l = b2 >> 8;
    int n = b2 & 255;
    const float* w = (l == 0) ? w0 : (l == 1) ? w1 : w2;
    _Float16* dst = wtp + (size_t)l * 256 * Kc;
    int g = n >> 4, col = n & 15;
    int cq = tid >> 6;
    int kk = tid & 63;
    int kq = kk >> 5;
    int k32 = kk & 31;
    int quad = k32 >> 3;
    int e = k32 & 7;
    const float* src = w + (size_t)n * 2304 + (size_t)tid * 9;
#pragma unroll
    for (int t = 0; t < 9; ++t) {
      int c = t * 4 + cq;
      size_t d = ((size_t)((c * 16 + g) * 2 + kq)) * 512 + (quad * 16 + col) * 8 + e;
      dst[d] = (_Float16)src[t];
    }
  } else {
    int b3 = bx - 4864;
    int l = b3 >> 5;
    int n = b3 & 31;
    const float* w = (l == 0) ? wo0 : (l == 1) ? wo1 : wo2;
    _Float16* dst = wbop + (size_t)l * 36 * 2048;
    int g = n >> 4, col = n & 15;
    int cw = tid >> 6;
    int r = tid & 63;
    int kq = r >> 5;
    int r2 = r & 31;
    int quad = r2 >> 3;
    int e = r2 & 7;
#pragma unroll
    for (int t = 0; t < 9; ++t) {
      int c = t * 4 + cw;
      size_t d = ((size_t)((c * 2 + g) * 2 + kq)) * 512 + (quad * 16 + col) * 8 + e;
      dst[d] = (n < 27) ? (_Float16)w[((size_t)n * 256 + tid) * 9 + t] : (_Float16)0.f;
    }
  }
}

// ---------------------------------------------------------------------------
// FUSED layer kernel. R12: 1024 threads = 16 waves (4/SIMD, 50% occupancy),
// role-split staging: tid<512 gather/repack A (same as R3), tid>=512 run the
// B depth-2 reg pipeline into Bs. ALL 16 waves compute. Per-chunk L2 bytes
// unchanged vs R3 (gathers 32K + B 32K); this isolates the occupancy lever:
// R0-R3 all sat at 2 waves/SIMD with ~1170cy/chunk of un-hidden latency
// (MfmaUtil ~= VALUBusy ~= 15.5%).
// Phase 2 wave split: mw(2) x nw(8): 32 rows x 32 cols, 8 MFMA/chunk/wave.
// Phase 1 compute on waves 0-7 only (M=64,N=32); waves 8-11 stage Bo.
// R9 XCD swizzle kept.
__global__ __launch_bounds__(1024, 4) void k_layer(
    const _Float16* __restrict__ xh,
    const _Float16* __restrict__ wbop, const float* __restrict__ boff,
    const _Float16* __restrict__ wtp, const float* __restrict__ bias,
    _Float16* __restrict__ outh, float* __restrict__ outf) {
  __shared__ __align__(16) _Float16 As[2][64][72];    // 18.4 KB
  __shared__ __align__(16) _Float16 Bs[2][16384];     // 64 KB
  __shared__ __align__(16) float omS[64 * 33];        // 8.4 KB
  __shared__ __align__(16) float sampS[64][9][8];     // 18 KB

  int bid = blockIdx.x;
  int lb = ((bid & 7) << 5) + (bid >> 3);   // XCD-contiguous logical block
  int p0 = lb * 64;
  int tid = threadIdx.x;       // 0..1023
  int lane = tid & 63;
  int wave = tid >> 6;         // 0..15
  int quad = lane >> 4;
  int col = lane & 15;

  bool isA = tid < 512;        // A-staging role (wave-uniform)
  int ar = (tid & 511) >> 3;   // staging/gather row 0..63 (A role)
  int aci = (tid & 7) * 8;     // 8-channel segment (A role)
  int t2 = tid & 511;          // B-staging thread id (B role)

  int p = p0 + ar;
  int bimg = p >> 12;
  int yx = p & 4095;
  int y = yx >> 6, x = yx & 63;

  half8 zero8;
#pragma unroll
  for (int e = 0; e < 8; ++e) zero8[e] = (_Float16)0.f;

  // ================= phase 1: offset conv (M=64,N=32,K=2304) =============
  int mi = (wave & 7) >> 1;   // 0..3 (16-row group), waves 0-7 only
  int ng = wave & 1;          // 0..1 (16-col group)

  floatx4 acc1 = (floatx4){0.f, 0.f, 0.f, 0.f};
  half8 ga = zero8;
  half8 bos0 = zero8, bos1 = zero8;  // B staging regs (waves 8-11)
  int abase = 0;
  bool avalid = false;
  bool isBo = (tid >= 512) && (tid < 768);
  {
    int sy = y - 1, sx = x - 1;
    avalid = (sy >= 0) & (sy < Hn) & (sx >= 0) & (sx < Wn);
    abase = (((bimg * Hn + (avalid ? sy : 0)) * Wn) + (avalid ? sx : 0)) * Cn;
    if (isA && avalid) ga = *(const half8*)(xh + (size_t)abase + aci);
    if (isBo) {
      bos0 = *(const half8*)(wbop + (size_t)t2 * 8);           // chunk 0
      bos1 = *(const half8*)(wbop + 2048 + (size_t)t2 * 8);    // chunk 1
    }
  }

  _Float16* Bo0 = &Bs[0][0];
  _Float16* Bo1 = &Bs[0][2048];

#pragma unroll 1
  for (int t = 0; t < 9; ++t) {
#pragma unroll
    for (int cc = 0; cc < 4; ++cc) {          // chunk c = 4t+cc; buf = cc&1
      // 1. stage A / B chunk c
      if (isA) {
        *(half8*)&As[cc & 1][ar][aci] = ga;
      } else if (isBo) {
        *(half8*)&((cc & 1) ? Bo1 : Bo0)[t2 * 8] = (cc & 1) ? bos1 : bos0;
      }
      // 2. issue next loads (stay in flight across barrier)
      if (isA) {
        if (cc < 3) {
          ga = zero8;
          if (avalid) ga = *(const half8*)(xh + (size_t)abase + (cc + 1) * 64 + aci);
        } else if (t < 8) {
          int tn = t + 1;
          int sy = y + tn / 3 - 1;
          int sx = x + tn % 3 - 1;
          avalid = (sy >= 0) & (sy < Hn) & (sx >= 0) & (sx < Wn);
          abase = (((bimg * Hn + (avalid ? sy : 0)) * Wn) + (avalid ? sx : 0)) * Cn;
          ga = zero8;
          if (avalid) ga = *(const half8*)(xh + (size_t)abase + aci);
        }
      } else if (isBo && (cc < 2 || t < 8)) {
        half8 v = *(const half8*)(wbop + ((size_t)(4 * t) + cc + 2) * 2048 + t2 * 8);
        if (cc & 1) bos1 = v; else bos0 = v;
      }

      __builtin_amdgcn_s_waitcnt(LGKM0);   // LDS visible; vmem NOT drained
      __builtin_amdgcn_s_barrier();

      if (isA) {
#pragma unroll
        for (int kq = 0; kq < 2; ++kq) {
          half8 af = *(const half8*)&As[cc & 1][mi * 16 + col][kq * 32 + quad * 8];
          half8 bf = *(const half8*)&((cc & 1) ? Bo1 : Bo0)[(ng * 2 + kq) * 512 + lane * 8];
          acc1 = __builtin_amdgcn_mfma_f32_16x16x32_f16(af, bf, acc1, 0, 0, 0);
        }
      }
    }
  }

  // om -> LDS (waves 0-7 hold the results)
  if (isA) {
    int n1 = ng * 16 + col;
    if (n1 < 27) {
      float bb = boff[n1];
#pragma unroll
      for (int r = 0; r < 4; ++r)
        omS[(mi * 16 + quad * 4 + r) * 33 + n1] = acc1[r] + bb;
    }
  }
  __syncthreads();

  // fused coords: 64 px x 9 taps = 576 entries -> sampS (LDS)
  if (tid < 576) {
    int e = tid;
    int lp = e / 9;
    int k = e - lp * 9;
    int pp = p0 + lp;
    int bi = pp >> 12;
    int pyx = pp & 4095;
    int py = pyx >> 6, px = pyx & 63;

    float dy = omS[lp * 33 + 2 * k];
    float dx = omS[lp * 33 + 2 * k + 1];
    float m = 1.f / (1.f + expf(-omS[lp * 33 + 18 + k]));

    float ys = (float)(py + k / 3 - 1) + dy;
    float xs = (float)(px + k % 3 - 1) + dx;
    float y0f = floorf(ys), x0f = floorf(xs);
    float wy = ys - y0f, wx = xs - x0f;
    int y0 = (int)y0f, x0 = (int)x0f;
    int y1 = y0 + 1, x1 = x0 + 1;

    bool vy0 = (y0 >= 0) & (y0 < Hn);
    bool vy1 = (y1 >= 0) & (y1 < Hn);
    bool vx0 = (x0 >= 0) & (x0 < Wn);
    bool vx1 = (x1 >= 0) & (x1 < Wn);
    int y0c = min(max(y0, 0), Hn - 1), y1c = min(max(y1, 0), Hn - 1);
    int x0c = min(max(x0, 0), Wn - 1), x1c = min(max(x1, 0), Wn - 1);

    int base = bi * HWn;
    float* s = &sampS[lp][k][0];
    ((int*)s)[0] = (base + y0c * Wn + x0c) * Cn;
    ((int*)s)[1] = (base + y0c * Wn + x1c) * Cn;
    ((int*)s)[2] = (base + y1c * Wn + x0c) * Cn;
    ((int*)s)[3] = (base + y1c * Wn + x1c) * Cn;
    s[4] = (vy0 && vx0) ? m * (1.f - wy) * (1.f - wx) : 0.f;
    s[5] = (vy0 && vx1) ? m * (1.f - wy) * wx : 0.f;
    s[6] = (vy1 && vx0) ? m * wy * (1.f - wx) : 0.f;
    s[7] = (vy1 && vx1) ? m * wy * wx : 0.f;
  }
  __syncthreads();

  // ================= phase 2: deformable main GEMM (M=64,N=256) ==========
  int mw = wave >> 3;          // 0..1 (32-row half)
  int nw = wave & 7;           // 0..7 (32-col group)

  float bj[2];
#pragma unroll
  for (int j = 0; j < 2; ++j) bj[j] = bias[(nw * 2 + j) * 16 + col];

  floatx4 acc[2][2];
#pragma unroll
  for (int i = 0; i < 2; ++i)
#pragma unroll
    for (int j = 0; j < 2; ++j) acc[i][j] = (floatx4){0.f, 0.f, 0.f, 0.f};

  half8 g00 = zero8, g01 = zero8, g10 = zero8, g11 = zero8;
  half8 bst0[4], bst1[4];      // B staging regs (tid>=512), depth-2
  int4 ofsC = {0, 0, 0, 0}, ofsN = {0, 0, 0, 0};
  float4 wvC = {0.f, 0.f, 0.f, 0.f}, wvN = wvC;

  // prologue: A role loads tap0 samp + chunk-0 gathers; B role loads chunks 0,1
  if (isA) {
    ofsC = *(const int4*)&sampS[ar][0][0];
    wvC = *(const float4*)&sampS[ar][0][4];
    ofsN = ofsC; wvN = wvC;
    g00 = *(const half8*)(xh + (size_t)ofsC.x + aci);
    g01 = *(const half8*)(xh + (size_t)ofsC.y + aci);
    g10 = *(const half8*)(xh + (size_t)ofsC.z + aci);
    g11 = *(const half8*)(xh + (size_t)ofsC.w + aci);
  } else {
#pragma unroll
    for (int q = 0; q < 4; ++q)
      bst0[q] = *(const half8*)(wtp + (size_t)(q * 512 + t2) * 8);
#pragma unroll
    for (int q = 0; q < 4; ++q)
      bst1[q] = *(const half8*)(wtp + 16384 + (size_t)(q * 512 + t2) * 8);
  }

#pragma unroll 1
  for (int t = 0; t < 9; ++t) {
    // next tap's samp entry (LDS; consumed at cc=3's gather issue)
    if (isA && t < 8) {
      ofsN = *(const int4*)&sampS[ar][t + 1][0];
      wvN = *(const float4*)&sampS[ar][t + 1][4];
    }
#pragma unroll
    for (int cc = 0; cc < 4; ++cc) {          // chunk c = 4t+cc; buf = cc&1
      // 1. stage chunk c (A role: repack+write; B role: reg->LDS)
      if (isA) {
        _Float16 h00 = (_Float16)wvC.x, h01 = (_Float16)wvC.y;
        _Float16 h10 = (_Float16)wvC.z, h11 = (_Float16)wvC.w;
        half8 r;
#pragma unroll
        for (int e = 0; e < 8; ++e)
          r[e] = g00[e] * h00 + g01[e] * h01 + g10[e] * h10 + g11[e] * h11;
        *(half8*)&As[cc & 1][ar][aci] = r;
      } else {
#pragma unroll
        for (int q = 0; q < 4; ++q)
          *(half8*)&Bs[cc & 1][(q * 512 + t2) * 8] = (cc & 1) ? bst1[q] : bst0[q];
      }
      // 2. issue chunk c+1 loads (stay in flight across barrier)
      if (isA) {
        if (cc < 3) {
          int ci = (cc + 1) * 64 + aci;
          g00 = *(const half8*)(xh + (size_t)ofsC.x + ci);
          g01 = *(const half8*)(xh + (size_t)ofsC.y + ci);
          g10 = *(const half8*)(xh + (size_t)ofsC.z + ci);
          g11 = *(const half8*)(xh + (size_t)ofsC.w + ci);
        } else if (t < 8) {
          g00 = *(const half8*)(xh + (size_t)ofsN.x + aci);
          g01 = *(const half8*)(xh + (size_t)ofsN.y + aci);
          g10 = *(const half8*)(xh + (size_t)ofsN.z + aci);
          g11 = *(const half8*)(xh + (size_t)ofsN.w + aci);
        }
      } else if (cc < 2 || t < 8) {
        const _Float16* wsrc = wtp + ((size_t)(4 * t) + cc + 2) * 16384;
#pragma unroll
        for (int q = 0; q < 4; ++q) {
          half8 v = *(const half8*)(wsrc + (size_t)(q * 512 + t2) * 8);
          if (cc & 1) bst1[q] = v; else bst0[q] = v;
        }
      }

      __builtin_amdgcn_s_waitcnt(LGKM0);   // LDS visible; vmem stays outstanding
      __builtin_amdgcn_s_barrier();

      half8 af[2][2];
#pragma unroll
      for (int kq = 0; kq < 2; ++kq)
#pragma unroll
        for (int i = 0; i < 2; ++i)
          af[kq][i] =
              *(const half8*)&As[cc & 1][mw * 32 + i * 16 + col][kq * 32 + quad * 8];

      half8 bf[2][2];
#pragma unroll
      for (int kq = 0; kq < 2; ++kq)
#pragma unroll
        for (int j = 0; j < 2; ++j)
          bf[kq][j] =
              *(const half8*)&Bs[cc & 1][((nw * 2 + j) * 2 + kq) * 512 + lane * 8];

#pragma unroll
      for (int kq = 0; kq < 2; ++kq)
#pragma unroll
        for (int i = 0; i < 2; ++i)
#pragma unroll
          for (int j = 0; j < 2; ++j)
            acc[i][j] = __builtin_amdgcn_mfma_f32_16x16x32_f16(
                af[kq][i], bf[kq][j], acc[i][j], 0, 0, 0);
    }
    ofsC = ofsN;
    wvC = wvN;
  }

  // epilogue: bias + relu. Hidden layers: f16 NHWC. Last layer: fp32 NCHW
  // direct to d_out (float4: 4 consecutive p = 4 consecutive x).
#pragma unroll
  for (int i = 0; i < 2; ++i)
#pragma unroll
    for (int j = 0; j < 2; ++j) {
      int n = (nw * 2 + j) * 16 + col;
      if (outf) {
        int pb = p0 + mw * 32 + i * 16 + quad * 4;
        int bi = pb >> 12;
        int pyx = pb & 4095;
        float4 v;
        v.x = fmaxf(acc[i][j][0] + bj[j], 0.f);
        v.y = fmaxf(acc[i][j][1] + bj[j], 0.f);
        v.z = fmaxf(acc[i][j][2] + bj[j], 0.f);
        v.w = fmaxf(acc[i][j][3] + bj[j], 0.f);
        *(float4*)(outf + ((size_t)(bi * On + n)) * HWn + pyx) = v;
      } else {
#pragma unroll
        for (int r = 0; r < 4; ++r) {
          int pp = p0 + mw * 32 + i * 16 + quad * 4 + r;
          float v = fmaxf(acc[i][j][r] + bj[j], 0.f);
          outh[(size_t)pp * On + n] = (_Float16)v;
        }
      }
    }
}

// ---------------------------------------------------------------------------
extern "C" void kernel_launch(void* const* d_in, const int* in_sizes, int n_in,
                              void* d_out, int out_size, void* d_ws, size_t ws_size,
                              hipStream_t stream) {
  (void)in_sizes; (void)n_in; (void)out_size; (void)ws_size;
  const float* x = (const float*)d_in[0];

  _Float16* act0h = (_Float16*)d_ws;                     // Pn*Cn f16
  _Float16* act1h = act0h + (size_t)Pn * Cn;             // Pn*Cn f16
  _Float16* wbop  = act1h + (size_t)Pn * Cn;             // 3*36*2048 f16
  _Float16* wtp   = wbop + (size_t)3 * 36 * 2048;        // 3*256*Kc f16

  k_init<<<4960, 256, 0, stream>>>(
      x, act0h,
      (const float*)d_in[3], (const float*)d_in[7], (const float*)d_in[11],
      (const float*)d_in[1], (const float*)d_in[5], (const float*)d_in[9],
      wtp, wbop);

  _Float16* cur = act0h;
  _Float16* nxt = act1h;
  for (int l = 0; l < 3; ++l) {
    const float* b_off = (const float*)d_in[2 + l * 4];
    const float* b     = (const float*)d_in[4 + l * 4];
    k_layer<<<Pn / 64, 1024, 0, stream>>>(
        cur, wbop + (size_t)l * 36 * 2048, b_off,
        wtp + (size_t)l * 256 * Kc, b, nxt,
        (l == 2) ? (float*)d_out : nullptr);
    _Float16* tswap = cur; cur = nxt; nxt = tswap;
  }
}

// Round 5
// 230.608 us; speedup vs baseline: 1.0095x; 1.0095x over previous
//
#include <hip/hip_runtime.h>
#include <math.h>

#define Bn 4
#define Cn 256
#define Hn 64
#define Wn 64
#define On 256
#define HWn 4096
#define Pn 16384   // B*H*W
#define Kc 2304    // 9*256

// s_waitcnt imm: vmcnt=63 (no wait), expcnt=7 (no wait), lgkmcnt=0 (drain LDS)
#define LGKM0 0xc07f

typedef _Float16 half8 __attribute__((ext_vector_type(8)));
typedef float floatx4 __attribute__((ext_vector_type(4)));

// ---------------------------------------------------------------------------
// ONE init kernel: blocks 0..4095 = fp32 NCHW -> f16 NHWC transpose;
// 4096..4863 = main-weight pack (layer l = (bx-4096)>>8, n = &255);
// 4864..4959 = offset-weight pack (layer l = (bx-4864)>>5, oc = &31).
__global__ void k_init(const float* __restrict__ x, _Float16* __restrict__ act0,
                       const float* __restrict__ w0, const float* __restrict__ w1,
                       const float* __restrict__ w2, const float* __restrict__ wo0,
                       const float* __restrict__ wo1, const float* __restrict__ wo2,
                       _Float16* __restrict__ wtp, _Float16* __restrict__ wbop) {
  int bx = blockIdx.x;
  int tid = threadIdx.x;
  if (bx < 4096) {
    // transpose tile: R=Cn rows, Cc=HWn cols; out[b][hw][ch] = in[b][ch][hw]
    __shared__ float tile[32][33];
    int cx = bx & 127, cy = (bx >> 7) & 7, b = bx >> 10;
    int c0 = cx * 32, r0 = cy * 32;
    int tx = tid & 31, ty = tid >> 5;
    const float* ib = x + (size_t)b * Cn * HWn;
    _Float16* ob = act0 + (size_t)b * Cn * HWn;
#pragma unroll
    for (int i = 0; i < 32; i += 8)
      tile[ty + i][tx] = ib[(size_t)(r0 + ty + i) * HWn + (c0 + tx)];
    __syncthreads();
#pragma unroll
    for (int i = 0; i < 32; i += 8)
      ob[(size_t)(c0 + ty + i) * Cn + (r0 + tx)] = (_Float16)tile[tx][ty + i];
  } else if (bx < 4864) {
    int b2 = bx - 4096;
    int l = b2 >> 8;
    int n = b2 & 255;
    const float* w = (l == 0) ? w0 : (l == 1) ? w1 : w2;
    _Float16* dst = wtp + (size_t)l * 256 * Kc;
    int g = n >> 4, col = n & 15;
    int cq = tid >> 6;
    int kk = tid & 63;
    int kq = kk >> 5;
    int k32 = kk & 31;
    int quad = k32 >> 3;
    int e = k32 & 7;
    const float* src = w + (size_t)n * 2304 + (size_t)tid * 9;
#pragma unroll
    for (int t = 0; t < 9; ++t) {
      int c = t * 4 + cq;
      size_t d = ((size_t)((c * 16 + g) * 2 + kq)) * 512 + (quad * 16 + col) * 8 + e;
      dst[d] = (_Float16)src[t];
    }
  } else {
    int b3 = bx - 4864;
    int l = b3 >> 5;
    int n = b3 & 31;
    const float* w = (l == 0) ? wo0 : (l == 1) ? wo1 : wo2;
    _Float16* dst = wbop + (size_t)l * 36 * 2048;
    int g = n >> 4, col = n & 15;
    int cw = tid >> 6;
    int r = tid & 63;
    int kq = r >> 5;
    int r2 = r & 31;
    int quad = r2 >> 3;
    int e = r2 & 7;
#pragma unroll
    for (int t = 0; t < 9; ++t) {
      int c = t * 4 + cw;
      size_t d = ((size_t)((c * 2 + g) * 2 + kq)) * 512 + (quad * 16 + col) * 8 + e;
      dst[d] = (n < 27) ? (_Float16)w[((size_t)n * 256 + tid) * 9 + t] : (_Float16)0.f;
    }
  }
}

// ---------------------------------------------------------------------------
// FUSED layer kernel: one block = 64 pixels, 512 threads (8 waves).
// R13: phase-2 PURE N-SPLIT: each wave owns 32 distinct output cols over all
//   64 rows; B fragments go L2 -> registers (depth-2 parity slots) with ZERO
//   cross-wave duplication (32KB/chunk, same as the LDS scheme). This deletes
//   the Bs write (32 instrs) + bf read (64 instrs) -> LDS wave-instrs/chunk
//   136 -> 72 (~860cy at b128 rate), attacking the LDS-throughput wall that
//   R3/R4 sat on, WITHOUT re-creating R2's 96KB/chunk L2 wall.
//   Diagnosis basis: R2 (no Bs, 96KB L2) = R3 (Bs, 64KB L2, 136 LDS instrs)
//   = R4 (168 instrs) = ~1700cy/chunk -> two walls of equal height.
// R11 rolled loops, R9 XCD swizzle kept. Phase 1 unchanged (small).
__global__ __launch_bounds__(512) void k_layer(
    const _Float16* __restrict__ xh,
    const _Float16* __restrict__ wbop, const float* __restrict__ boff,
    const _Float16* __restrict__ wtp, const float* __restrict__ bias,
    _Float16* __restrict__ outh, float* __restrict__ outf) {
  __shared__ __align__(16) _Float16 As[2][64][72];    // 18.4 KB
  __shared__ __align__(16) _Float16 BoS[2][2048];     // 8 KB (phase 1 B)
  __shared__ __align__(16) float omS[64 * 33];        // 8.4 KB
  __shared__ __align__(16) float sampS[64][9][8];     // 18 KB

  int bid = blockIdx.x;
  int lb = ((bid & 7) << 5) + (bid >> 3);   // XCD-contiguous logical block
  int p0 = lb * 64;
  int tid = threadIdx.x;       // 0..511
  int lane = tid & 63;
  int wave = tid >> 6;         // 0..7
  int quad = lane >> 4;
  int col = lane & 15;

  int ar = tid >> 3;           // staging/gather row 0..63
  int aci = (tid & 7) * 8;     // 8-channel segment

  int p = p0 + ar;
  int bimg = p >> 12;
  int yx = p & 4095;
  int y = yx >> 6, x = yx & 63;

  half8 zero8;
#pragma unroll
  for (int e = 0; e < 8; ++e) zero8[e] = (_Float16)0.f;

  // ================= phase 1: offset conv (M=64,N=32,K=2304) =============
  int mi = wave >> 1;   // 0..3 (16-row group)
  int ng = wave & 1;    // 0..1 (16-col group)

  floatx4 acc1 = (floatx4){0.f, 0.f, 0.f, 0.f};
  half8 ga;
  half8 bos0, bos1;     // B staging regs, chunk-parity slots (depth-2)
  int abase = 0;
  bool avalid = false;
  {
    int sy = y - 1, sx = x - 1;
    avalid = (sy >= 0) & (sy < Hn) & (sx >= 0) & (sx < Wn);
    abase = (((bimg * Hn + (avalid ? sy : 0)) * Wn) + (avalid ? sx : 0)) * Cn;
    ga = zero8;
    if (avalid) ga = *(const half8*)(xh + (size_t)abase + aci);
    bos0 = zero8; bos1 = zero8;
    if (tid < 256) {
      bos0 = *(const half8*)(wbop + (size_t)tid * 8);           // chunk 0
      bos1 = *(const half8*)(wbop + 2048 + (size_t)tid * 8);    // chunk 1
    }
  }

#pragma unroll 1
  for (int t = 0; t < 9; ++t) {
#pragma unroll
    for (int cc = 0; cc < 4; ++cc) {          // chunk c = 4t+cc; buf = cc&1
      // 1. stage A chunk c (vm-waits the ga load only; bos stays in flight)
      *(half8*)&As[cc & 1][ar][aci] = ga;
      // 2. stage B chunk c from reg slot (loaded at iter c-2; no vm wait)
      if (tid < 256)
        *(half8*)&BoS[cc & 1][tid * 8] = (cc & 1) ? bos1 : bos0;
      // 3. issue A load for chunk c+1
      if (cc < 3) {
        ga = zero8;
        if (avalid) ga = *(const half8*)(xh + (size_t)abase + (cc + 1) * 64 + aci);
      } else if (t < 8) {
        int tn = t + 1;
        int sy = y + tn / 3 - 1;
        int sx = x + tn % 3 - 1;
        avalid = (sy >= 0) & (sy < Hn) & (sx >= 0) & (sx < Wn);
        abase = (((bimg * Hn + (avalid ? sy : 0)) * Wn) + (avalid ? sx : 0)) * Cn;
        ga = zero8;
        if (avalid) ga = *(const half8*)(xh + (size_t)abase + aci);
      }
      // 4. refill B slot with chunk c+2 (exists iff 4t+cc+2 <= 35)
      if ((cc < 2 || t < 8) && tid < 256) {
        half8 v = *(const half8*)(wbop + ((size_t)(4 * t) + cc + 2) * 2048 + tid * 8);
        if (cc & 1) bos1 = v; else bos0 = v;
      }

      __builtin_amdgcn_s_waitcnt(LGKM0);   // LDS visible; vmem NOT drained
      __builtin_amdgcn_s_barrier();

#pragma unroll
      for (int kq = 0; kq < 2; ++kq) {
        half8 af = *(const half8*)&As[cc & 1][mi * 16 + col][kq * 32 + quad * 8];
        half8 bf = *(const half8*)&BoS[cc & 1][(ng * 2 + kq) * 512 + lane * 8];
        acc1 = __builtin_amdgcn_mfma_f32_16x16x32_f16(af, bf, acc1, 0, 0, 0);
      }
    }
  }

  // om -> LDS
  {
    int n1 = ng * 16 + col;
    if (n1 < 27) {
      float bb = boff[n1];
#pragma unroll
      for (int r = 0; r < 4; ++r)
        omS[(mi * 16 + quad * 4 + r) * 33 + n1] = acc1[r] + bb;
    }
  }
  __syncthreads();

  // fused coords: 64 px x 9 taps = 576 entries -> sampS (LDS)
  for (int e = tid; e < 576; e += 512) {
    int lp = e / 9;
    int k = e - lp * 9;
    int pp = p0 + lp;
    int bi = pp >> 12;
    int pyx = pp & 4095;
    int py = pyx >> 6, px = pyx & 63;

    float dy = omS[lp * 33 + 2 * k];
    float dx = omS[lp * 33 + 2 * k + 1];
    float m = 1.f / (1.f + expf(-omS[lp * 33 + 18 + k]));

    float ys = (float)(py + k / 3 - 1) + dy;
    float xs = (float)(px + k % 3 - 1) + dx;
    float y0f = floorf(ys), x0f = floorf(xs);
    float wy = ys - y0f, wx = xs - x0f;
    int y0 = (int)y0f, x0 = (int)x0f;
    int y1 = y0 + 1, x1 = x0 + 1;

    bool vy0 = (y0 >= 0) & (y0 < Hn);
    bool vy1 = (y1 >= 0) & (y1 < Hn);
    bool vx0 = (x0 >= 0) & (x0 < Wn);
    bool vx1 = (x1 >= 0) & (x1 < Wn);
    int y0c = min(max(y0, 0), Hn - 1), y1c = min(max(y1, 0), Hn - 1);
    int x0c = min(max(x0, 0), Wn - 1), x1c = min(max(x1, 0), Wn - 1);

    int base = bi * HWn;
    float* s = &sampS[lp][k][0];
    ((int*)s)[0] = (base + y0c * Wn + x0c) * Cn;
    ((int*)s)[1] = (base + y0c * Wn + x1c) * Cn;
    ((int*)s)[2] = (base + y1c * Wn + x0c) * Cn;
    ((int*)s)[3] = (base + y1c * Wn + x1c) * Cn;
    s[4] = (vy0 && vx0) ? m * (1.f - wy) * (1.f - wx) : 0.f;
    s[5] = (vy0 && vx1) ? m * (1.f - wy) * wx : 0.f;
    s[6] = (vy1 && vx0) ? m * wy * (1.f - wx) : 0.f;
    s[7] = (vy1 && vx1) ? m * wy * wx : 0.f;
  }
  __syncthreads();

  // ================= phase 2: deformable main GEMM (M=64,N=256) ==========
  // Pure N-split: wave w owns cols [w*32, w*32+32), all 64 rows.
  float bj[2];
#pragma unroll
  for (int j = 0; j < 2; ++j) bj[j] = bias[(wave * 2 + j) * 16 + col];

  floatx4 acc[4][2];
#pragma unroll
  for (int i = 0; i < 4; ++i)
#pragma unroll
    for (int j = 0; j < 2; ++j) acc[i][j] = (floatx4){0.f, 0.f, 0.f, 0.f};

  half8 g00, g01, g10, g11;
  half8 bwA[2][2], bwB[2][2];  // B fragment regs [kq][j], chunk-parity slots
  int4 ofsC, ofsN;
  float4 wvC, wvN;

  // prologue: tap0 samp; gathers for chunk 0; B chunks 0 and 1 into regs
  ofsC = *(const int4*)&sampS[ar][0][0];
  wvC = *(const float4*)&sampS[ar][0][4];
  ofsN = ofsC; wvN = wvC;
  g00 = *(const half8*)(xh + (size_t)ofsC.x + aci);
  g01 = *(const half8*)(xh + (size_t)ofsC.y + aci);
  g10 = *(const half8*)(xh + (size_t)ofsC.z + aci);
  g11 = *(const half8*)(xh + (size_t)ofsC.w + aci);
#pragma unroll
  for (int kq = 0; kq < 2; ++kq)
#pragma unroll
    for (int j = 0; j < 2; ++j) {
      bwA[kq][j] = *(const half8*)(wtp +
          (size_t)((wave * 2 + j) * 2 + kq) * 512 + lane * 8);
      bwB[kq][j] = *(const half8*)(wtp + 16384 +
          (size_t)((wave * 2 + j) * 2 + kq) * 512 + lane * 8);
    }

#pragma unroll 1
  for (int t = 0; t < 9; ++t) {
    // next tap's samp entry (LDS; consumed at cc=3's gather issue)
    if (t < 8) {
      ofsN = *(const int4*)&sampS[ar][t + 1][0];
      wvN = *(const float4*)&sampS[ar][t + 1][4];
    }
#pragma unroll
    for (int cc = 0; cc < 4; ++cc) {          // chunk c = 4t+cc; buf = cc&1
      // 1. stage A chunk c (vm-waits the 4 gather loads only)
      {
        _Float16 h00 = (_Float16)wvC.x, h01 = (_Float16)wvC.y;
        _Float16 h10 = (_Float16)wvC.z, h11 = (_Float16)wvC.w;
        half8 r;
#pragma unroll
        for (int e = 0; e < 8; ++e)
          r[e] = g00[e] * h00 + g01[e] * h01 + g10[e] * h10 + g11[e] * h11;
        *(half8*)&As[cc & 1][ar][aci] = r;
      }
      // 2. issue gathers for chunk c+1 (stay in flight across barrier)
      if (cc < 3) {
        int ci = (cc + 1) * 64 + aci;
        g00 = *(const half8*)(xh + (size_t)ofsC.x + ci);
        g01 = *(const half8*)(xh + (size_t)ofsC.y + ci);
        g10 = *(const half8*)(xh + (size_t)ofsC.z + ci);
        g11 = *(const half8*)(xh + (size_t)ofsC.w + ci);
      } else if (t < 8) {
        g00 = *(const half8*)(xh + (size_t)ofsN.x + aci);
        g01 = *(const half8*)(xh + (size_t)ofsN.y + aci);
        g10 = *(const half8*)(xh + (size_t)ofsN.z + aci);
        g11 = *(const half8*)(xh + (size_t)ofsN.w + aci);
      }

      __builtin_amdgcn_s_waitcnt(LGKM0);   // LDS visible; vmem stays outstanding
      __builtin_amdgcn_s_barrier();

      half8 af[2][4];
#pragma unroll
      for (int kq = 0; kq < 2; ++kq)
#pragma unroll
        for (int i = 0; i < 4; ++i)
          af[kq][i] =
              *(const half8*)&As[cc & 1][i * 16 + col][kq * 32 + quad * 8];

#pragma unroll
      for (int kq = 0; kq < 2; ++kq)
#pragma unroll
        for (int i = 0; i < 4; ++i)
#pragma unroll
          for (int j = 0; j < 2; ++j)
            acc[i][j] = __builtin_amdgcn_mfma_f32_16x16x32_f16(
                af[kq][i], (cc & 1) ? bwB[kq][j] : bwA[kq][j], acc[i][j], 0, 0, 0);

      // 3. refill the just-consumed parity slot with chunk c+2
      //    (issued here, consumed 2 chunk-times later -> deep slack)
      if (cc < 2 || t < 8) {
        const _Float16* wsrc = wtp + ((size_t)(4 * t) + cc + 2) * 16384;
#pragma unroll
        for (int kq = 0; kq < 2; ++kq)
#pragma unroll
          for (int j = 0; j < 2; ++j) {
            half8 v = *(const half8*)(wsrc +
                (size_t)((wave * 2 + j) * 2 + kq) * 512 + lane * 8);
            if (cc & 1) bwB[kq][j] = v; else bwA[kq][j] = v;
          }
      }
    }
    ofsC = ofsN;
    wvC = wvN;
  }

  // epilogue: bias + relu. Hidden layers: f16 NHWC. Last layer: fp32 NCHW
  // direct to d_out (float4: 4 consecutive p = 4 consecutive x).
#pragma unroll
  for (int i = 0; i < 4; ++i)
#pragma unroll
    for (int j = 0; j < 2; ++j) {
      int n = (wave * 2 + j) * 16 + col;
      if (outf) {
        int pb = p0 + i * 16 + quad * 4;
        int bi = pb >> 12;
        int pyx = pb & 4095;
        float4 v;
        v.x = fmaxf(acc[i][j][0] + bj[j], 0.f);
        v.y = fmaxf(acc[i][j][1] + bj[j], 0.f);
        v.z = fmaxf(acc[i][j][2] + bj[j], 0.f);
        v.w = fmaxf(acc[i][j][3] + bj[j], 0.f);
        *(float4*)(outf + ((size_t)(bi * On + n)) * HWn + pyx) = v;
      } else {
#pragma unroll
        for (int r = 0; r < 4; ++r) {
          int pp = p0 + i * 16 + quad * 4 + r;
          float v = fmaxf(acc[i][j][r] + bj[j], 0.f);
          outh[(size_t)pp * On + n] = (_Float16)v;
        }
      }
    }
}

// ---------------------------------------------------------------------------
extern "C" void kernel_launch(void* const* d_in, const int* in_sizes, int n_in,
                              void* d_out, int out_size, void* d_ws, size_t ws_size,
                              hipStream_t stream) {
  (void)in_sizes; (void)n_in; (void)out_size; (void)ws_size;
  const float* x = (const float*)d_in[0];

  _Float16* act0h = (_Float16*)d_ws;                     // Pn*Cn f16
  _Float16* act1h = act0h + (size_t)Pn * Cn;             // Pn*Cn f16
  _Float16* wbop  = act1h + (size_t)Pn * Cn;             // 3*36*2048 f16
  _Float16* wtp   = wbop + (size_t)3 * 36 * 2048;        // 3*256*Kc f16

  k_init<<<4960, 256, 0, stream>>>(
      x, act0h,
      (const float*)d_in[3], (const float*)d_in[7], (const float*)d_in[11],
      (const float*)d_in[1], (const float*)d_in[5], (const float*)d_in[9],
      wtp, wbop);

  _Float16* cur = act0h;
  _Float16* nxt = act1h;
  for (int l = 0; l < 3; ++l) {
    const float* b_off = (const float*)d_in[2 + l * 4];
    const float* b     = (const float*)d_in[4 + l * 4];
    k_layer<<<Pn / 64, 512, 0, stream>>>(
        cur, wbop + (size_t)l * 36 * 2048, b_off,
        wtp + (size_t)l * 256 * Kc, b, nxt,
        (l == 2) ? (float*)d_out : nullptr);
    _Float16* tswap = cur; cur = nxt; nxt = tswap;
  }
}